// Round 7
// baseline (1022.040 us; speedup 1.0000x reference)
//
#include <hip/hip_runtime.h>
#include <math.h>

#define BATCH 256
#define CH 512
#define SE_CH 32
#define HW 1024
#define NBLK 256
#define PPB 8                    // planes per block per round
#define ROUNDS 64                // 131072 planes / (256*8)
#define GRP 64                   // blocks per batch sync group
#define RPLANES (NBLK * PPB)     // planes per round = 2048

typedef float f32x4 __attribute__((ext_vector_type(4)));

__device__ __forceinline__ void gload_lds16(const float* gsrc, float* ldst) {
    __builtin_amdgcn_global_load_lds(
        (const __attribute__((address_space(1))) void*)gsrc,
        (__attribute__((address_space(3))) void*)ldst, 16, 0, 0);
}

// One-pass SE block, LDS-staged, counted-vmcnt pipeline.
// 256 blocks x 1024 threads, 1 block/CU (128KB LDS) -> all co-resident.
__global__ __launch_bounds__(1024) void se_pipe(
        const float* __restrict__ x,
        float* __restrict__ out,
        const float* __restrict__ fc1_w,   // [SE_CH][CH]
        const float* __restrict__ fc1_b,   // [SE_CH]
        const float* __restrict__ fc2_w,   // [2*CH][SE_CH]
        const float* __restrict__ fc2_b,   // [2*CH]
        float* __restrict__ yacc,          // [BATCH][SE_CH], zeroed per call
        int* __restrict__ flags) {         // [BATCH], zeroed per call
    const int t = threadIdx.x;
    const int w = t >> 6;          // wave 0..15
    const int lane = t & 63;
    const int i = (int)blockIdx.x;
    const int c0 = (i & 63) * PPB; // this block's channel offset within its batch

    __shared__ __align__(16) float buf[4][PPB][HW];   // 128 KB, 4-deep ring
    __shared__ float m[PPB];
    __shared__ float sev[SE_CH];
    __shared__ float sc[PPB];
    __shared__ float bo[PPB];

    // ---- hoist all FC weights into registers (no global loads in the loop) ----
    // wave 0, FC1: lane l -> output o=l>>1, half hf=l&1, 4 weights
    float w10 = 0.f, w11 = 0.f, w12 = 0.f, w13 = 0.f, fb = 0.f;
    if (w == 0) {
        const int o = lane >> 1, hf = lane & 1;
        const float* p = fc1_w + o * CH + c0 + hf * 4;
        w10 = p[0]; w11 = p[1]; w12 = p[2]; w13 = p[3];
        if (lane < SE_CH) fb = fc1_b[lane];
    }
    // FC2: threads 0..511: row16 = t>>5 (0..15 -> 8 scale + 8 bias rows), k = t&31
    float w2v = 0.f, b2 = 0.f;
    if (t < 512) {
        const int row16 = t >> 5, k = t & 31;
        const int grow = (row16 < PPB) ? (c0 + row16) : (CH + c0 + row16 - PPB);
        w2v = fc2_w[grow * SE_CH + k];
        if (k == 0) b2 = fc2_b[grow];
    }

    // ---- prologue: prefetch rounds 0 and 1 (wave w owns half-plane w) ----
    {
        const int p = w >> 1, hf = w & 1;
        for (int q = 0; q < 2; ++q) {
            const size_t gp = (size_t)q * RPLANES + (size_t)i * PPB + p;
            const float* src = x + gp * HW + hf * 512 + lane * 4;
            float* dst = &buf[q][p][hf * 512];
            gload_lds16(src, dst);
            gload_lds16(src + 256, dst + 256);
        }
    }

    for (int r = 0; r <= ROUNDS; ++r) {
        // ---- wait for pf(r) (counted: never drain the deeper prefetch) ----
        if (r < ROUNDS) {
            if (r < 2)
                asm volatile("s_waitcnt vmcnt(2)" ::: "memory");
            else if (r == 2 || r == ROUNDS - 1)
                asm volatile("s_waitcnt vmcnt(4)" ::: "memory");
            else
                asm volatile("s_waitcnt vmcnt(6)" ::: "memory");
        }
        __builtin_amdgcn_s_barrier();   // all waves' pf(r) shares now in LDS

        // ---- issue pf(r+2) into buf[(r+2)&3] ----
        if (r + 2 < ROUNDS) {
            const int q = r + 2;
            const int p = w >> 1, hf = w & 1;
            const size_t gp = (size_t)q * RPLANES + (size_t)i * PPB + p;
            const float* src = x + gp * HW + hf * 512 + lane * 4;
            float* dst = &buf[q & 3][p][hf * 512];
            gload_lds16(src, dst);
            gload_lds16(src + 256, dst + 256);
        }

        // ---- means(r): waves 8..15, wave 8+p reduces plane p ----
        if (r < ROUNDS && w >= 8) {
            const int p = w - 8;
            const float* bp = &buf[r & 3][p][0];
            float s = 0.f;
#pragma unroll
            for (int q2 = 0; q2 < 4; ++q2) {
                f32x4 v = *(const f32x4*)(bp + q2 * 256 + lane * 4);
                s += (v.x + v.y) + (v.z + v.w);
            }
#pragma unroll
            for (int off = 32; off; off >>= 1)
                s += __shfl_xor(s, off, 64);
            if (lane == 0)
                m[p] = s * (1.0f / 1024.0f);
        }
        asm volatile("s_waitcnt lgkmcnt(0)" ::: "memory");
        __builtin_amdgcn_s_barrier();   // m[] visible

        // ---- wave 0: FC1 partial + flag(r); spin + sev for batch(r-1) ----
        if (w == 0) {
            if (r < ROUNDS) {
                const int b = (r * RPLANES + i * PPB) >> 9;
                const int hf = lane & 1;
                const float* mm = &m[hf * 4];
                float acc = w10 * mm[0] + w11 * mm[1] + w12 * mm[2] + w13 * mm[3];
                acc += __shfl_xor(acc, 1, 64);
                if (hf == 0) {
                    const int o = lane >> 1;
                    __hip_atomic_fetch_add(&yacc[b * SE_CH + o], acc,
                                           __ATOMIC_RELAXED, __HIP_MEMORY_SCOPE_AGENT);
                }
                if (t == 0)
                    __hip_atomic_fetch_add(&flags[b], 1,
                                           __ATOMIC_RELEASE, __HIP_MEMORY_SCOPE_AGENT);
            }
            if (r >= 1) {
                const int bp_ = ((r - 1) * RPLANES + i * PPB) >> 9;
                if (t == 0) {
                    while (__hip_atomic_load(&flags[bp_], __ATOMIC_ACQUIRE,
                                             __HIP_MEMORY_SCOPE_AGENT) < GRP)
                        __builtin_amdgcn_s_sleep(1);
                }
                if (lane < SE_CH) {
                    float y = __hip_atomic_load(&yacc[bp_ * SE_CH + lane],
                                                __ATOMIC_RELAXED, __HIP_MEMORY_SCOPE_AGENT);
                    sev[lane] = fmaxf(y + fb, 0.f);
                }
            }
        }
        asm volatile("s_waitcnt lgkmcnt(0)" ::: "memory");
        __builtin_amdgcn_s_barrier();   // sev[] visible; batch(r-1) FC1 complete

        // ---- FC2 for batch(r-1): threads 0..511, hoisted weights ----
        if (r >= 1 && t < 512) {
            const int row16 = t >> 5, k = t & 31;
            float acc = w2v * sev[k];
#pragma unroll
            for (int off = 16; off; off >>= 1)
                acc += __shfl_xor(acc, off, 32);
            if (k == 0) {
                acc += b2;
                if (row16 < PPB)
                    sc[row16] = 1.0f / (1.0f + expf(-acc));
                else
                    bo[row16 - PPB] = acc;
            }
        }
        asm volatile("s_waitcnt lgkmcnt(0)" ::: "memory");
        __builtin_amdgcn_s_barrier();   // sc/bo visible

        // ---- apply(r-1) from buf[(r-1)&3], nontemporal store ----
        if (r >= 1) {
            const int p = w >> 1, hf = w & 1;
            const float s = sc[p];
            const float bb = bo[p];
            const size_t gp = (size_t)(r - 1) * RPLANES + (size_t)i * PPB + p;
            const float* bp2 = &buf[(r - 1) & 3][p][hf * 512];
            float* op = out + gp * HW + hf * 512;
#pragma unroll
            for (int j = 0; j < 2; ++j) {
                f32x4 v = *(const f32x4*)(bp2 + j * 256 + lane * 4);
                f32x4 rr;
                rr.x = fmaf(v.x, s, bb);
                rr.y = fmaf(v.y, s, bb);
                rr.z = fmaf(v.z, s, bb);
                rr.w = fmaf(v.w, s, bb);
                __builtin_nontemporal_store(rr, (f32x4*)(op + j * 256 + lane * 4));
            }
        }
    }
}

extern "C" void kernel_launch(void* const* d_in, const int* in_sizes, int n_in,
                              void* d_out, int out_size, void* d_ws, size_t ws_size,
                              hipStream_t stream) {
    const float* x     = (const float*)d_in[0];
    const float* fc1_w = (const float*)d_in[1];
    const float* fc1_b = (const float*)d_in[2];
    const float* fc2_w = (const float*)d_in[3];
    const float* fc2_b = (const float*)d_in[4];
    float* out = (float*)d_out;

    float* yacc = (float*)d_ws;                                         // 32 KB
    int* flags  = (int*)((char*)d_ws + BATCH * SE_CH * sizeof(float));  // 1 KB

    hipMemsetAsync(d_ws, 0, BATCH * SE_CH * sizeof(float) + BATCH * sizeof(int),
                   stream);

    se_pipe<<<NBLK, 1024, 0, stream>>>(x, out, fc1_w, fc1_b, fc2_w, fc2_b,
                                       yacc, flags);
}

// Round 8
// 287.114 us; speedup vs baseline: 3.5597x; 3.5597x over previous
//
#include <hip/hip_runtime.h>
#include <math.h>

#define BATCH 256
#define CH 512
#define SE_CH 32
#define HW 1024                       // 32*32
#define CHUNK_B 16                    // 16 batches = 32 MB per chunk
#define NCHUNK (BATCH / CHUNK_B)      // 16
#define CP (CHUNK_B * CH)             // 8192 planes per chunk

typedef float f32x4 __attribute__((ext_vector_type(4)));

// Fused pipeline kernel, role split by blockIdx.
//   blockIdx < na           : apply chunk at apply_b0 (FC recomputed per block)
//   blockIdx in [na, grid)  : plane means for [mean_p0, mean_p0+mean_np)
// Cache discipline: mean reads allocate (re-used by next dispatch's apply);
// apply reads + out writes are nontemporal (last touch / no reuse).
__global__ __launch_bounds__(256) void se_fused(
        const float* __restrict__ x,
        float* __restrict__ out,
        float* __restrict__ mean_ws,          // [BATCH*CH]
        const float* __restrict__ fc1_w,      // [SE_CH][CH]
        const float* __restrict__ fc1_b,      // [SE_CH]
        const float* __restrict__ fc2_w,      // [2*CH][SE_CH]
        const float* __restrict__ fc2_b,      // [2*CH]
        int na, int subs_lg, int apply_b0, int mean_p0, int mean_np) {
    const int t = threadIdx.x;
    const int bid = (int)blockIdx.x;

    if (bid < na) {
        // ---------------- apply role ----------------
        __shared__ float m[CH];
        __shared__ float sev[SE_CH];
        __shared__ float sc[256];
        __shared__ float bi[256];

        const int subs = 1 << subs_lg;
        const int cps = CH >> subs_lg;             // channels per block
        const int b = apply_b0 + (bid >> subs_lg); // batch element
        const int sub = bid & (subs - 1);          // channel slice

        for (int i = t; i < CH; i += 256)
            m[i] = mean_ws[(size_t)b * CH + i];
        __syncthreads();

        // FC1: output o = t>>3, partial p = t&7 over k = p+8j (bank-conflict-free)
        {
            const int o = t >> 3;
            const int p = t & 7;
            const float* wr = fc1_w + o * CH;
            float acc = 0.0f;
#pragma unroll
            for (int j = 0; j < 64; ++j) {
                const int k = p + 8 * j;
                acc = fmaf(wr[k], m[k], acc);
            }
            acc += __shfl_xor(acc, 4, 8);
            acc += __shfl_xor(acc, 2, 8);
            acc += __shfl_xor(acc, 1, 8);
            if (p == 0)
                sev[o] = fmaxf(acc + fc1_b[o], 0.0f);
        }
        __syncthreads();

        // FC2: this block's cps scale + cps bias outputs
        if (t < 2 * cps) {
            const int cl = t & (cps - 1);
            const int c = sub * cps + cl;
            const int o = (t < cps) ? c : (CH + c);
            float acc = fc2_b[o];
            const float* wr = fc2_w + o * SE_CH;
#pragma unroll
            for (int k = 0; k < SE_CH; ++k)
                acc = fmaf(wr[k], sev[k], acc);
            if (t < cps)
                sc[cl] = 1.0f / (1.0f + expf(-acc));
            else
                bi[cl] = acc;
        }
        __syncthreads();

        // apply cps planes; thread t does f32x4 #t of each plane
        const size_t base = ((size_t)b * CH + (size_t)sub * cps) * HW;
        const f32x4* xp = (const f32x4*)(x + base);
        f32x4* op = (f32x4*)(out + base);
        for (int p = 0; p < cps; ++p) {
            const float s = sc[p];
            const float bb = bi[p];
            f32x4 v = __builtin_nontemporal_load(&xp[p * 256 + t]);
            f32x4 r;
            r.x = fmaf(v.x, s, bb);
            r.y = fmaf(v.y, s, bb);
            r.z = fmaf(v.z, s, bb);
            r.w = fmaf(v.w, s, bb);
            __builtin_nontemporal_store(r, &op[p * 256 + t]);
        }
    } else {
        // ---------------- mean role ----------------
        // Regular (allocating) loads: data re-read by next dispatch's apply.
        const int lane = t & 63;
        const int wib = t >> 6;
        const int rid = bid - na;
        const int nw = ((int)gridDim.x - na) * 4;
        const int wid = rid * 4 + wib;
        for (int p = wid; p < mean_np; p += nw) {
            const f32x4* px = (const f32x4*)(x + (size_t)(mean_p0 + p) * HW);
            float s = 0.0f;
#pragma unroll
            for (int j = 0; j < 4; ++j) {
                f32x4 v = px[lane + j * 64];
                s += (v.x + v.y) + (v.z + v.w);
            }
#pragma unroll
            for (int off = 32; off; off >>= 1)
                s += __shfl_xor(s, off, 64);
            if (lane == 0)
                mean_ws[mean_p0 + p] = s * (1.0f / 1024.0f);
        }
    }
}

extern "C" void kernel_launch(void* const* d_in, const int* in_sizes, int n_in,
                              void* d_out, int out_size, void* d_ws, size_t ws_size,
                              hipStream_t stream) {
    const float* x     = (const float*)d_in[0];
    const float* fc1_w = (const float*)d_in[1];
    const float* fc1_b = (const float*)d_in[2];
    const float* fc2_w = (const float*)d_in[3];
    const float* fc2_b = (const float*)d_in[4];
    float* out = (float*)d_out;
    float* mean = (float*)d_ws;   // BATCH*CH f32

    // Prologue: means of chunk 0, full machine.
    se_fused<<<2048, 256, 0, stream>>>(x, out, mean, fc1_w, fc1_b, fc2_w, fc2_b,
                                       0, 0, 0, 0, CP);

    // Steady state: apply(k) with 512 blocks (subs=32, 16 planes/block),
    // mean(k+1) with 1536 blocks.
    for (int k = 0; k < NCHUNK - 1; ++k) {
        se_fused<<<2048, 256, 0, stream>>>(
            x, out, mean, fc1_w, fc1_b, fc2_w, fc2_b,
            512, 5, k * CHUNK_B, (k + 1) * CP, CP);
    }

    // Epilogue: apply last chunk with the whole grid (subs=128, 4 planes/block).
    se_fused<<<2048, 256, 0, stream>>>(
        x, out, mean, fc1_w, fc1_b, fc2_w, fc2_b,
        2048, 7, (NCHUNK - 1) * CHUNK_B, 0, 0);
}

// Round 9
// 285.621 us; speedup vs baseline: 3.5783x; 1.0052x over previous
//
#include <hip/hip_runtime.h>
#include <math.h>

#define BATCH 256
#define CH 512
#define SE_CH 32
#define HW 1024                       // 32*32
#define CHUNK_B 32                    // 32 batches = 64 MB per chunk
#define NCHUNK (BATCH / CHUNK_B)      // 8
#define CP (CHUNK_B * CH)             // 16384 planes per chunk

typedef float f32x4 __attribute__((ext_vector_type(4)));

// Fused pipeline kernel, role split by blockIdx.
//   blockIdx < na           : apply chunk at apply_b0 (FC recomputed per block)
//   blockIdx in [na, grid)  : plane means for [mean_p0, mean_p0+mean_np)
// Cache discipline: mean reads allocate L3 (re-used by next dispatch's apply);
// apply reads are REGULAR (must look up L3 -- NT reads bypass it, r5/r8 bug);
// out writes are nontemporal (never re-read, don't evict the incoming chunk).
__global__ __launch_bounds__(256) void se_fused(
        const float* __restrict__ x,
        float* __restrict__ out,
        float* __restrict__ mean_ws,          // [BATCH*CH]
        const float* __restrict__ fc1_w,      // [SE_CH][CH]
        const float* __restrict__ fc1_b,      // [SE_CH]
        const float* __restrict__ fc2_w,      // [2*CH][SE_CH]
        const float* __restrict__ fc2_b,      // [2*CH]
        int na, int subs_lg, int apply_b0, int mean_p0, int mean_np) {
    const int t = threadIdx.x;
    const int bid = (int)blockIdx.x;

    if (bid < na) {
        // ---------------- apply role ----------------
        __shared__ float m[CH];
        __shared__ float sev[SE_CH];
        __shared__ float sc[256];
        __shared__ float bi[256];

        const int subs = 1 << subs_lg;
        const int cps = CH >> subs_lg;             // channels per block
        const int b = apply_b0 + (bid >> subs_lg); // batch element
        const int sub = bid & (subs - 1);          // channel slice

        for (int i = t; i < CH; i += 256)
            m[i] = mean_ws[(size_t)b * CH + i];
        __syncthreads();

        // FC1: output o = t>>3, partial p = t&7 over k = p+8j (bank-conflict-free)
        {
            const int o = t >> 3;
            const int p = t & 7;
            const float* wr = fc1_w + o * CH;
            float acc = 0.0f;
#pragma unroll
            for (int j = 0; j < 64; ++j) {
                const int k = p + 8 * j;
                acc = fmaf(wr[k], m[k], acc);
            }
            acc += __shfl_xor(acc, 4, 8);
            acc += __shfl_xor(acc, 2, 8);
            acc += __shfl_xor(acc, 1, 8);
            if (p == 0)
                sev[o] = fmaxf(acc + fc1_b[o], 0.0f);
        }
        __syncthreads();

        // FC2: this block's cps scale + cps bias outputs
        if (t < 2 * cps) {
            const int cl = t & (cps - 1);
            const int c = sub * cps + cl;
            const int o = (t < cps) ? c : (CH + c);
            float acc = fc2_b[o];
            const float* wr = fc2_w + o * SE_CH;
#pragma unroll
            for (int k = 0; k < SE_CH; ++k)
                acc = fmaf(wr[k], sev[k], acc);
            if (t < cps)
                sc[cl] = 1.0f / (1.0f + expf(-acc));
            else
                bi[cl] = acc;
        }
        __syncthreads();

        // apply cps planes; thread t does f32x4 #t of each plane.
        // REGULAR loads: hit the chunk the previous dispatch's mean role
        // pulled into Infinity Cache.
        const size_t base = ((size_t)b * CH + (size_t)sub * cps) * HW;
        const f32x4* xp = (const f32x4*)(x + base);
        f32x4* op = (f32x4*)(out + base);
        for (int p = 0; p < cps; ++p) {
            const float s = sc[p];
            const float bb = bi[p];
            f32x4 v = xp[p * 256 + t];
            f32x4 r;
            r.x = fmaf(v.x, s, bb);
            r.y = fmaf(v.y, s, bb);
            r.z = fmaf(v.z, s, bb);
            r.w = fmaf(v.w, s, bb);
            __builtin_nontemporal_store(r, &op[p * 256 + t]);
        }
    } else {
        // ---------------- mean role ----------------
        // Regular (allocating) loads: data re-read by next dispatch's apply.
        const int lane = t & 63;
        const int wib = t >> 6;
        const int rid = bid - na;
        const int nw = ((int)gridDim.x - na) * 4;
        const int wid = rid * 4 + wib;
        for (int p = wid; p < mean_np; p += nw) {
            const f32x4* px = (const f32x4*)(x + (size_t)(mean_p0 + p) * HW);
            float s = 0.0f;
#pragma unroll
            for (int j = 0; j < 4; ++j) {
                f32x4 v = px[lane + j * 64];
                s += (v.x + v.y) + (v.z + v.w);
            }
#pragma unroll
            for (int off = 32; off; off >>= 1)
                s += __shfl_xor(s, off, 64);
            if (lane == 0)
                mean_ws[mean_p0 + p] = s * (1.0f / 1024.0f);
        }
    }
}

extern "C" void kernel_launch(void* const* d_in, const int* in_sizes, int n_in,
                              void* d_out, int out_size, void* d_ws, size_t ws_size,
                              hipStream_t stream) {
    const float* x     = (const float*)d_in[0];
    const float* fc1_w = (const float*)d_in[1];
    const float* fc1_b = (const float*)d_in[2];
    const float* fc2_w = (const float*)d_in[3];
    const float* fc2_b = (const float*)d_in[4];
    float* out = (float*)d_out;
    float* mean = (float*)d_ws;   // BATCH*CH f32

    // Prologue: means of chunk 0, full machine.
    se_fused<<<2048, 256, 0, stream>>>(x, out, mean, fc1_w, fc1_b, fc2_w, fc2_b,
                                       0, 0, 0, 0, CP);

    // Steady state: apply(k) with 1024 blocks (subs=32, 16 planes/block),
    // mean(k+1) with 1024 blocks (16 planes/wave).
    for (int k = 0; k < NCHUNK - 1; ++k) {
        se_fused<<<2048, 256, 0, stream>>>(
            x, out, mean, fc1_w, fc1_b, fc2_w, fc2_b,
            1024, 5, k * CHUNK_B, (k + 1) * CP, CP);
    }

    // Epilogue: apply last chunk with the whole grid (subs=64, 8 planes/block).
    se_fused<<<2048, 256, 0, stream>>>(
        x, out, mean, fc1_w, fc1_b, fc2_w, fc2_b,
        2048, 6, (NCHUNK - 1) * CHUNK_B, 0, 0);
}